// Round 7
// baseline (4482.028 us; speedup 1.0000x reference)
//
#include <hip/hip_runtime.h>
#include <math.h>

typedef _Float16 f16;
typedef _Float16 f16x8 __attribute__((ext_vector_type(8)));
typedef float f32x4 __attribute__((ext_vector_type(4)));

// Problem dims
#define T_ 1024
#define B_ 128
#define DI_ 256
#define DL_ 512
#define V_ 10000

// ws layout (bytes)
#define OFF_EMBH   0u          // V*DI fp16 = 5,120,000
#define OFF_WIT    5120000u    // [512][256] fp16 = 262,144 (WiT[n][k] = Wi[k][n])
#define OFF_WFRAG  5382144u    // 32 tiles x 16 kk x 64 lanes x 8 f16 = 524,288 (frag-linear Wh)
#define OFF_BSUM   5906432u    // 512 f32 = 2048 (bi + bh)

// fast tanh: 1 - 2/(exp(2x)+1). No clamp needed: exp2->inf gives 1, ->0 gives -1.
__device__ __forceinline__ float fast_tanh(float x) {
  float e = __builtin_amdgcn_exp2f(x * 2.88539008177793f);  // exp(2x)
  return 1.f - 2.f * __builtin_amdgcn_rcpf(e + 1.f);
}

// ---------------- prep kernels ----------------
__global__ void prep_emb_k(const float* __restrict__ emb, f16* __restrict__ embH, int n) {
  for (int i = blockIdx.x * blockDim.x + threadIdx.x; i < n; i += gridDim.x * blockDim.x)
    embH[i] = (f16)emb[i];
}

// WiT[n][k] = Wi[k][n]; Wfrag fragment-linear Wh; bsum = bi + bh
__global__ void prep_w_k(const float* __restrict__ Wi, const float* __restrict__ Wh,
                         const float* __restrict__ bi, const float* __restrict__ bh,
                         f16* __restrict__ WiT, f16* __restrict__ Wfrag,
                         float* __restrict__ bsum) {
  int i = blockIdx.x * blockDim.x + threadIdx.x;
  if (i < 131072) {                       // WiT
    int n = i & 511, k = i >> 9;
    WiT[n * 256 + k] = (f16)Wi[k * 512 + n];
  } else if (i < 131072 + 32768) {        // Wfrag[ct][kk][l][8]
    int s = i - 131072;
    int l = s & 63, kk = (s >> 6) & 15, ct = s >> 10;
    int n = ct * 16 + (l & 15);
    int kbase = kk * 32 + (l >> 4) * 8;
    f16 tmp[8];
#pragma unroll
    for (int e = 0; e < 8; e++) tmp[e] = (f16)Wh[(size_t)(kbase + e) * 512 + n];
    *(f16x8*)&Wfrag[(size_t)s * 8] = *(f16x8*)tmp;
  } else if (i < 131072 + 32768 + 512) {  // bsum
    int s = i - 131072 - 32768;
    bsum[s] = bi[s] + bh[s];
  }
}

// ---------------- phase A: PREfrag = gather(embH,X) @ Wi + bsum ----------------
// Output layout (overlaid on d_out): float offset t*65536 + c*8192 + ct*256 + lane*4 + r
__global__ __launch_bounds__(256) void gemmA_k(
    const int* __restrict__ X, const f16* __restrict__ embH,
    const f16* __restrict__ WiT, const float* __restrict__ bsum,
    float* __restrict__ out) {
  __shared__ f16 Ah[128][40];
  __shared__ f16 Bh[128][40];
  __shared__ int idxL[128];

  int tid = threadIdx.x;
  int lane = tid & 63, w = tid >> 6;
  int wr = w >> 1, wc = w & 1;
  int by = blockIdx.y, bx = blockIdx.x;
  int m0 = by * 128, n0 = bx * 128;

  if (tid < 128) {
    int v = X[m0 + tid];
    idxL[tid] = (v < 0) ? 0 : ((v >= V_) ? (V_ - 1) : v);
  }
  __syncthreads();

  f32x4 acc[4][4];
#pragma unroll
  for (int i = 0; i < 4; i++)
#pragma unroll
    for (int jj = 0; jj < 4; jj++) acc[i][jj] = (f32x4){0.f, 0.f, 0.f, 0.f};

  int ar = lane & 15, koff = (lane >> 4) * 8;

  for (int kk = 0; kk < 8; kk++) {
    int k0 = kk * 32;
#pragma unroll
    for (int q = 0; q < 2; q++) {
      int s = tid + 256 * q;
      int row = s >> 2, part = s & 3;
      *(uint4*)&Ah[row][part * 8] = *(const uint4*)&embH[idxL[row] * 256 + k0 + part * 8];
      *(uint4*)&Bh[row][part * 8] = *(const uint4*)&WiT[(n0 + row) * 256 + k0 + part * 8];
    }
    __syncthreads();
    f16x8 a[4], b[4];
#pragma unroll
    for (int i = 0; i < 4; i++) a[i] = *(const f16x8*)&Ah[wr * 64 + i * 16 + ar][koff];
#pragma unroll
    for (int jj = 0; jj < 4; jj++) b[jj] = *(const f16x8*)&Bh[wc * 64 + jj * 16 + ar][koff];
#pragma unroll
    for (int i = 0; i < 4; i++)
#pragma unroll
      for (int jj = 0; jj < 4; jj++)
        acc[i][jj] = __builtin_amdgcn_mfma_f32_16x16x32_f16(a[i], b[jj], acc[i][jj], 0, 0, 0);
    __syncthreads();
  }

#pragma unroll
  for (int i = 0; i < 4; i++) {
#pragma unroll
    for (int jj = 0; jj < 4; jj++) {
      int c = wr * 4 + i;
      int ct = bx * 8 + wc * 4 + jj;
      float bs = bsum[ct * 16 + ar];
      f32x4 v = acc[i][jj];
      v[0] += bs; v[1] += bs; v[2] += bs; v[3] += bs;
      *(f32x4*)&out[(size_t)by * 65536 + (size_t)c * 8192 + ct * 256 + lane * 4] = v;
    }
  }
}

// ---------------- phase B: persistent recurrence, ZERO inter-WG comms ----------------
// 8 WGs x 512 threads (8 waves -> 2 waves/SIMD at <=256 regs). Wave w owns
// col-tiles 4w..4w+3: tiles 4w,4w+1 VGPR-resident (128 regs), tile 4w+2
// LDS-resident (8 tiles = 128 KB), tile 4w+3 streamed from XCD-L2 with a
// rolling 4-deep prefetch (stream addresses are constant across steps, so the
// pipeline never restarts). PRE is double-buffered across two unrolled steps,
// issued at kk==2 so its HBM latency never hits the barrier drain.
// h kept in LDS fragment-linear (hA); PRE read from / H written to the same
// (t,c) 32 KB block of d_out (intra-WG overlay, barrier-ordered).
#define RNN_STEP(T, PCUR, PNXT)                                               \
  {                                                                           \
    __syncthreads(); /* B1: hA(t-1) visible; drains in-flight vmem */         \
    f32x4 acc[4] = {{0.f,0.f,0.f,0.f},{0.f,0.f,0.f,0.f},                      \
                    {0.f,0.f,0.f,0.f},{0.f,0.f,0.f,0.f}};                     \
    int tn_ = (T) + 1; if (tn_ >= 1024) tn_ = 0; /* dummy on last step */     \
    const f32x4* pb_ = (const f32x4*)(H + (size_t)tn_ * 65536 + (size_t)c * 8192); \
    _Pragma("unroll")                                                         \
    for (int kk = 0; kk < 16; kk++) {                                         \
      f16x8 a_  = *(const f16x8*)&hA[(kk * 64 + lane) * 8];                   \
      f16x8 wl_ = *(const f16x8*)&Wlds[((w * 16 + kk) * 64 + lane) * 8];      \
      acc[0] = __builtin_amdgcn_mfma_f32_16x16x32_f16(a_, Wreg[kk],      acc[0], 0, 0, 0); \
      acc[1] = __builtin_amdgcn_mfma_f32_16x16x32_f16(a_, Wreg[16 + kk], acc[1], 0, 0, 0); \
      acc[2] = __builtin_amdgcn_mfma_f32_16x16x32_f16(a_, wl_,           acc[2], 0, 0, 0); \
      acc[3] = __builtin_amdgcn_mfma_f32_16x16x32_f16(a_, ws[kk & 3],    acc[3], 0, 0, 0); \
      ws[kk & 3] = Wfr[sbase + (((kk + 4) & 15) << 6)]; /* refill freed slot */ \
      if (kk == 2) {                                                          \
        PNXT[0] = pb_[(w4 + 0) * 64 + lane];                                  \
        PNXT[1] = pb_[(w4 + 1) * 64 + lane];                                  \
        PNXT[2] = pb_[(w4 + 2) * 64 + lane];                                  \
        PNXT[3] = pb_[(w4 + 3) * 64 + lane];                                  \
      }                                                                       \
    }                                                                         \
    __syncthreads(); /* B2: hA(t-1) reads done -> safe to overwrite */        \
    float* Hblk_ = H + (size_t)(T) * 65536 + (size_t)c * 8192;                \
    _Pragma("unroll")                                                         \
    for (int ti = 0; ti < 4; ti++) {                                          \
      int ct_ = w4 + ti;                                                      \
      int base_ = ((ct_ >> 1) * 64) << 3;                                     \
      int hi_ = (((ct_ & 1) << 1) | (ar >> 3)) << 4;                          \
      _Pragma("unroll")                                                       \
      for (int r = 0; r < 4; r++) {                                           \
        float v_ = fast_tanh(acc[ti][r] + PCUR[ti][r]);                       \
        Hblk_[(size_t)(r0 + r) * 512 + ct_ * 16 + ar] = v_;                   \
        hA[base_ + (((r0 + r) | hi_) << 3) + (ar & 7)] = (f16)v_;             \
      }                                                                       \
    }                                                                         \
  }

__global__ __launch_bounds__(512, 2) void rnnB_k(
    const float* __restrict__ h0, const f16* __restrict__ Wfrag,
    float* __restrict__ H) {
  __shared__ f16 Wlds[8 * 16 * 64 * 8];  // 131072 B: slot w <-> tile 4w+2
  __shared__ f16 hA[16 * 64 * 8];        // 16384 B: frag-linear h ([kk][lane][8])

  int tid = threadIdx.x, lane = tid & 63, w = tid >> 6;
  int c = blockIdx.x;          // batch slice: rows c*16..c*16+15
  int w4 = w * 4;
  int ar = lane & 15, r0 = (lane >> 4) * 4;

  const f16x8* Wfr = (const f16x8*)Wfrag;  // index: (ct*16+kk)*64 + lane

  // one-time: LDS weight slots (slot s <- tile 4s+2)
  for (int idx = tid; idx < 8192; idx += 512) {
    int l = idx & 63, kk = (idx >> 6) & 15, s = idx >> 10;
    *(f16x8*)&Wlds[(size_t)idx * 8] = Wfr[((s * 4 + 2) * 16 + kk) * 64 + l];
  }
  // one-time: hA <- h0 (frag-linear scatter)
  for (int idx = tid; idx < 8192; idx += 512) {
    int kk = idx >> 9, l = (idx >> 3) & 63, e = idx & 7;
    int row = l & 15, k = kk * 32 + (l >> 4) * 8 + e;
    hA[idx] = (f16)h0[(size_t)(c * 16 + row) * 512 + k];
  }

  // one-time: register-resident weight tiles 4w, 4w+1 (128 VGPR, static-indexed)
  f16x8 Wreg[32];
#pragma unroll
  for (int ti = 0; ti < 2; ti++)
#pragma unroll
    for (int kk = 0; kk < 16; kk++)
      Wreg[ti * 16 + kk] = Wfr[((w4 + ti) * 16 + kk) * 64 + lane];

  // stream tile 4w+3: rolling 4-deep prefetch (same 16 addresses every step)
  int sbase = ((w4 + 3) * 16) * 64 + lane;
  f16x8 ws[4];
#pragma unroll
  for (int i = 0; i < 4; i++) ws[i] = Wfr[sbase + (i << 6)];

  // prologue: pre(t=0)
  f32x4 preA[4], preB[4];
  {
    const f32x4* pb = (const f32x4*)(H + (size_t)c * 8192);
#pragma unroll
    for (int ti = 0; ti < 4; ti++) preA[ti] = pb[(w4 + ti) * 64 + lane];
  }

  for (int s = 0; s < 512; s++) {
    RNN_STEP(2 * s,     preA, preB)   // k-loop issues preB <- PRE(2s+1)
    RNN_STEP(2 * s + 1, preB, preA)   // k-loop issues preA <- PRE(2s+2)
  }
}

// ---------------- launch ----------------
extern "C" void kernel_launch(void* const* d_in, const int* in_sizes, int n_in,
                              void* d_out, int out_size, void* d_ws, size_t ws_size,
                              hipStream_t stream) {
  const int* X     = (const int*)d_in[0];   // int32 (harness stores integer inputs as int32)
  const float* h0  = (const float*)d_in[1];
  const float* emb = (const float*)d_in[2];
  const float* Wi  = (const float*)d_in[3];
  const float* bi  = (const float*)d_in[4];
  const float* Wh  = (const float*)d_in[5];
  const float* bh  = (const float*)d_in[6];
  float* H = (float*)d_out;

  char* ws = (char*)d_ws;
  f16* embH   = (f16*)(ws + OFF_EMBH);
  f16* WiT    = (f16*)(ws + OFF_WIT);
  f16* Wfrag  = (f16*)(ws + OFF_WFRAG);
  float* bsum = (float*)(ws + OFF_BSUM);

  prep_emb_k<<<2560, 256, 0, stream>>>(emb, embH, V_ * DI_);
  prep_w_k<<<642, 256, 0, stream>>>(Wi, Wh, bi, bh, WiT, Wfrag, bsum);
  gemmA_k<<<dim3(4, 1024), 256, 0, stream>>>(X, embH, WiT, bsum, H);
  rnnB_k<<<8, 512, 0, stream>>>(h0, Wfrag, H);
}

// Round 9
// 4388.023 us; speedup vs baseline: 1.0214x; 1.0214x over previous
//
#include <hip/hip_runtime.h>
#include <math.h>

typedef _Float16 f16;
typedef _Float16 f16x4 __attribute__((ext_vector_type(4)));
typedef _Float16 f16x8 __attribute__((ext_vector_type(8)));
typedef float f32x4 __attribute__((ext_vector_type(4)));

// Problem dims
#define T_ 1024
#define B_ 128
#define DI_ 256
#define DL_ 512
#define V_ 10000

// ws layout (bytes)
#define OFF_EMBH   0u          // V*DI fp16 = 5,120,000
#define OFF_WIT    5120000u    // [512][256] fp16 = 262,144 (WiT[n][k] = Wi[k][n])
#define OFF_WFRAG  5382144u    // 32 tiles x 16 kk x 64 lanes x 8 f16 = 524,288 (frag-linear Wh)
#define OFF_BSUM   5906432u    // 512 f32 = 2048 (bi + bh)

// fast tanh: 1 - 2/(exp(2x)+1). No clamp needed: exp2->inf gives 1, ->0 gives -1.
__device__ __forceinline__ float fast_tanh(float x) {
  float e = __builtin_amdgcn_exp2f(x * 2.88539008177793f);  // exp(2x)
  return 1.f - 2.f * __builtin_amdgcn_rcpf(e + 1.f);
}

// ---------------- prep kernels ----------------
__global__ void prep_emb_k(const float* __restrict__ emb, f16* __restrict__ embH, int n) {
  for (int i = blockIdx.x * blockDim.x + threadIdx.x; i < n; i += gridDim.x * blockDim.x)
    embH[i] = (f16)emb[i];
}

// WiT[n][k] = Wi[k][n]; Wfrag fragment-linear Wh (A/B-operand [n][k] layout); bsum = bi+bh
__global__ void prep_w_k(const float* __restrict__ Wi, const float* __restrict__ Wh,
                         const float* __restrict__ bi, const float* __restrict__ bh,
                         f16* __restrict__ WiT, f16* __restrict__ Wfrag,
                         float* __restrict__ bsum) {
  int i = blockIdx.x * blockDim.x + threadIdx.x;
  if (i < 131072) {                       // WiT
    int n = i & 511, k = i >> 9;
    WiT[n * 256 + k] = (f16)Wi[k * 512 + n];
  } else if (i < 131072 + 32768) {        // Wfrag[ct][kk][l][8]: lane l holds Wh[kbase+e][ct*16+(l&15)]
    int s = i - 131072;
    int l = s & 63, kk = (s >> 6) & 15, ct = s >> 10;
    int n = ct * 16 + (l & 15);
    int kbase = kk * 32 + (l >> 4) * 8;
    f16 tmp[8];
#pragma unroll
    for (int e = 0; e < 8; e++) tmp[e] = (f16)Wh[(size_t)(kbase + e) * 512 + n];
    *(f16x8*)&Wfrag[(size_t)s * 8] = *(f16x8*)tmp;
  } else if (i < 131072 + 32768 + 512) {  // bsum
    int s = i - 131072 - 32768;
    bsum[s] = bi[s] + bh[s];
  }
}

// ---------------- phase A: PREfrag = gather(embH,X) @ Wi + bsum ----------------
// SWAPPED MFMA (A=Wi fragment, B=emb fragment) -> D[n][m]: thread holds
// m=lane&15 (batch row), n=(lane>>4)*4+r (4 consecutive cols).
// PREfrag slot formula (shared with rnnB): t*65536 + c*8192 + ct*256 + lane*4 + r.
__global__ __launch_bounds__(256) void gemmA_k(
    const int* __restrict__ X, const f16* __restrict__ embH,
    const f16* __restrict__ WiT, const float* __restrict__ bsum,
    float* __restrict__ out) {
  __shared__ f16 Ah[128][40];
  __shared__ f16 Bh[128][40];
  __shared__ int idxL[128];

  int tid = threadIdx.x;
  int lane = tid & 63, w = tid >> 6;
  int wr = w >> 1, wc = w & 1;
  int by = blockIdx.y, bx = blockIdx.x;
  int m0 = by * 128, n0 = bx * 128;

  if (tid < 128) {
    int v = X[m0 + tid];
    idxL[tid] = (v < 0) ? 0 : ((v >= V_) ? (V_ - 1) : v);
  }
  __syncthreads();

  f32x4 acc[4][4];
#pragma unroll
  for (int i = 0; i < 4; i++)
#pragma unroll
    for (int jj = 0; jj < 4; jj++) acc[i][jj] = (f32x4){0.f, 0.f, 0.f, 0.f};

  int ar = lane & 15, koff = (lane >> 4) * 8, r0 = (lane >> 4) * 4;

  for (int kk = 0; kk < 8; kk++) {
    int k0 = kk * 32;
#pragma unroll
    for (int q = 0; q < 2; q++) {
      int s = tid + 256 * q;
      int row = s >> 2, part = s & 3;
      *(uint4*)&Ah[row][part * 8] = *(const uint4*)&embH[idxL[row] * 256 + k0 + part * 8];
      *(uint4*)&Bh[row][part * 8] = *(const uint4*)&WiT[(n0 + row) * 256 + k0 + part * 8];
    }
    __syncthreads();
    f16x8 a[4], b[4];
#pragma unroll
    for (int i = 0; i < 4; i++) a[i] = *(const f16x8*)&Ah[wr * 64 + i * 16 + ar][koff];
#pragma unroll
    for (int jj = 0; jj < 4; jj++) b[jj] = *(const f16x8*)&Bh[wc * 64 + jj * 16 + ar][koff];
#pragma unroll
    for (int i = 0; i < 4; i++)
#pragma unroll
      for (int jj = 0; jj < 4; jj++)   // SWAPPED: A=WiT frag, B=emb frag -> D[n][m]
        acc[i][jj] = __builtin_amdgcn_mfma_f32_16x16x32_f16(b[jj], a[i], acc[i][jj], 0, 0, 0);
    __syncthreads();
  }

#pragma unroll
  for (int i = 0; i < 4; i++) {
#pragma unroll
    for (int jj = 0; jj < 4; jj++) {
      int c = wr * 4 + i;
      int ct = bx * 8 + wc * 4 + jj;
      f32x4 bsv = *(const f32x4*)&bsum[ct * 16 + r0];  // cols vary with r now
      f32x4 v = acc[i][jj];
      v[0] += bsv[0]; v[1] += bsv[1]; v[2] += bsv[2]; v[3] += bsv[3];
      *(f32x4*)&out[(size_t)by * 65536 + (size_t)c * 8192 + ct * 256 + lane * 4] = v;
    }
  }
}

// ---------------- phase B: persistent recurrence, ZERO inter-WG comms ----------------
// 8 WGs x 512 threads (2 waves/SIMD, 256-reg unified budget). Wave w owns
// col-tiles 4w..4w+3: tiles 4w,4w+1 pinned in AGPRs ("a" asm constraints --
// allocator cannot remat them), tile 4w+2 LDS-resident (8 tiles = 128 KB),
// tile 4w+3 streamed from L2 with an 8-deep rolling prefetch.
// Inline-asm MFMA hazard contract (LLVM can't see inside asm):
//   - first kk uses the C=0 inline-constant form (no VALU-init -> SrcC hazard)
//   - s_nop fence (data-dep ordered via "+v") before any VALU read of asm accs
#define RNN_STEP(T, PCUR, PNXT)                                               \
  {                                                                           \
    __syncthreads(); /* B1: hA(t-1) writes visible; drains all vmem */        \
    f32x4 acc0, acc1;                                                         \
    f32x4 acc2 = {0.f,0.f,0.f,0.f}, acc3 = {0.f,0.f,0.f,0.f};                 \
    int tn_ = (T) + 1; if (tn_ >= 1024) tn_ = 0; /* dummy on last step */     \
    const f32x4* pb_ = (const f32x4*)(H + (size_t)tn_ * 65536 + (size_t)c * 8192); \
    _Pragma("unroll")                                                         \
    for (int kk = 0; kk < 16; kk++) {                                         \
      f16x8 a_  = *(const f16x8*)&hA[(kk * 64 + lane) * 8];                   \
      f16x8 wl_ = *(const f16x8*)&Wlds[((w * 16 + kk) * 64 + lane) * 8];      \
      if (kk == 0) {                                                          \
        asm("v_mfma_f32_16x16x32_f16 %0, %1, %2, 0"                           \
            : "=v"(acc0) : "a"(wa[0]), "v"(a_));                              \
        asm("v_mfma_f32_16x16x32_f16 %0, %1, %2, 0"                           \
            : "=v"(acc1) : "a"(wa[16]), "v"(a_));                             \
      } else {                                                                \
        asm("v_mfma_f32_16x16x32_f16 %0, %1, %2, %0"                          \
            : "+v"(acc0) : "a"(wa[kk]), "v"(a_));                             \
        asm("v_mfma_f32_16x16x32_f16 %0, %1, %2, %0"                          \
            : "+v"(acc1) : "a"(wa[16 + kk]), "v"(a_));                        \
      }                                                                       \
      acc2 = __builtin_amdgcn_mfma_f32_16x16x32_f16(wl_, a_, acc2, 0, 0, 0);  \
      acc3 = __builtin_amdgcn_mfma_f32_16x16x32_f16(ws[kk & 7], a_, acc3, 0, 0, 0); \
      ws[kk & 7] = Wfr[sbase + (((kk + 8) & 15) << 6)];                       \
      if (kk == 2) {                                                          \
        PNXT[0] = pb_[(w4 + 0) * 64 + lane];                                  \
        PNXT[1] = pb_[(w4 + 1) * 64 + lane];                                  \
        PNXT[2] = pb_[(w4 + 2) * 64 + lane];                                  \
        PNXT[3] = pb_[(w4 + 3) * 64 + lane];                                  \
      }                                                                       \
    }                                                                         \
    /* MFMA(asm)->VALU read wait-state fence: 24 cycles, dep-ordered */       \
    asm("s_nop 7\n\ts_nop 7\n\ts_nop 7" : "+v"(acc0), "+v"(acc1));            \
    __syncthreads(); /* B2: hA(t-1) reads done -> safe to overwrite */        \
    float* Hrow_ = H + (size_t)(T) * 65536 + (size_t)c * 8192 + (size_t)(lane & 15) * 512; \
    f32x4 accs_[4] = {acc0, acc1, acc2, acc3};                                \
    _Pragma("unroll")                                                         \
    for (int q = 0; q < 4; q++) {                                             \
      int ti = (q + 2) & 3; /* builtin accs first (extra hazard spacing) */   \
      int ct_ = w4 + ti;                                                      \
      f32x4 o_; f16 hp_[4];                                                   \
      _Pragma("unroll")                                                       \
      for (int r = 0; r < 4; r++) {                                           \
        float v_ = fast_tanh(accs_[ti][r] + PCUR[ti][r]);                     \
        o_[r] = v_; hp_[r] = (f16)v_;                                         \
      }                                                                       \
      *(f32x4*)&Hrow_[ct_ * 16 + r0] = o_;                                    \
      int kH_ = ct_ * 16 + r0;                                                \
      int lH_ = (lane & 15) | (((kH_ >> 3) & 3) << 4);                        \
      *(f16x4*)&hA[(((kH_ >> 5) * 64 + lH_) << 3) + (kH_ & 7)] = *(f16x4*)hp_; \
    }                                                                         \
  }

__global__ void __launch_bounds__(512)
    __attribute__((amdgpu_waves_per_eu(2, 2))) rnnB_k(
    const float* __restrict__ h0, const f16* __restrict__ Wfrag,
    float* __restrict__ H) {
  __shared__ f16 Wlds[8 * 16 * 64 * 8];  // 131072 B: slot w <-> tile 4w+2
  __shared__ f16 hA[16 * 64 * 8];        // 16384 B: frag-linear h ([kk][lane][8])

  int tid = threadIdx.x, lane = tid & 63, w = tid >> 6;
  int c = blockIdx.x;          // batch slice: rows c*16..c*16+15
  int w4 = w * 4;
  int r0 = (lane >> 4) * 4;

  const f16x8* Wfr = (const f16x8*)Wfrag;  // index: (ct*16+kk)*64 + lane

  // one-time: LDS weight slots (slot s <- tile 4s+2)
  for (int idx = tid; idx < 8192; idx += 512) {
    int l = idx & 63, kk = (idx >> 6) & 15, s = idx >> 10;
    *(f16x8*)&Wlds[(size_t)idx * 8] = Wfr[((s * 4 + 2) * 16 + kk) * 64 + l];
  }
  // one-time: hA <- h0 (frag-linear scatter)
  for (int idx = tid; idx < 8192; idx += 512) {
    int kk = idx >> 9, l = (idx >> 3) & 63, e = idx & 7;
    int row = l & 15, k = kk * 32 + (l >> 4) * 8 + e;
    hA[idx] = (f16)h0[(size_t)(c * 16 + row) * 512 + k];
  }

  // one-time: AGPR-pinned weight tiles 4w, 4w+1 (128 AGPRs via "a" uses below)
  f16x8 wa[32];
#pragma unroll
  for (int ti = 0; ti < 2; ti++)
#pragma unroll
    for (int kk = 0; kk < 16; kk++)
      wa[ti * 16 + kk] = Wfr[((w4 + ti) * 16 + kk) * 64 + lane];

  // stream tile 4w+3: 8-deep rolling prefetch (same 16 addresses every step)
  int sbase = ((w4 + 3) * 16) * 64 + lane;
  f16x8 ws[8];
#pragma unroll
  for (int i = 0; i < 8; i++) ws[i] = Wfr[sbase + (i << 6)];

  // prologue: pre(t=0)
  f32x4 preA[4], preB[4];
  {
    const f32x4* pb = (const f32x4*)(H + (size_t)c * 8192);
#pragma unroll
    for (int ti = 0; ti < 4; ti++) preA[ti] = pb[(w4 + ti) * 64 + lane];
  }

  for (int s = 0; s < 512; s++) {
    RNN_STEP(2 * s,     preA, preB)   // k-loop issues preB <- PRE(2s+1)
    RNN_STEP(2 * s + 1, preB, preA)   // k-loop issues preA <- PRE(2s+2)
  }
}

// ---------------- launch ----------------
extern "C" void kernel_launch(void* const* d_in, const int* in_sizes, int n_in,
                              void* d_out, int out_size, void* d_ws, size_t ws_size,
                              hipStream_t stream) {
  const int* X     = (const int*)d_in[0];   // int32 (harness stores integer inputs as int32)
  const float* h0  = (const float*)d_in[1];
  const float* emb = (const float*)d_in[2];
  const float* Wi  = (const float*)d_in[3];
  const float* bi  = (const float*)d_in[4];
  const float* Wh  = (const float*)d_in[5];
  const float* bh  = (const float*)d_in[6];
  float* H = (float*)d_out;

  char* ws = (char*)d_ws;
  f16* embH   = (f16*)(ws + OFF_EMBH);
  f16* WiT    = (f16*)(ws + OFF_WIT);
  f16* Wfrag  = (f16*)(ws + OFF_WFRAG);
  float* bsum = (float*)(ws + OFF_BSUM);

  prep_emb_k<<<2560, 256, 0, stream>>>(emb, embH, V_ * DI_);
  prep_w_k<<<642, 256, 0, stream>>>(Wi, Wh, bi, bh, WiT, Wfrag, bsum);
  gemmA_k<<<dim3(4, 1024), 256, 0, stream>>>(X, embH, WiT, bsum, H);
  rnnB_k<<<8, 512, 0, stream>>>(h0, Wfrag, H);
}

// Round 10
// 3999.260 us; speedup vs baseline: 1.1207x; 1.0972x over previous
//
#include <hip/hip_runtime.h>
#include <math.h>

typedef _Float16 f16;
typedef _Float16 f16x4 __attribute__((ext_vector_type(4)));
typedef _Float16 f16x8 __attribute__((ext_vector_type(8)));
typedef float f32x4 __attribute__((ext_vector_type(4)));

// Problem dims
#define T_ 1024
#define B_ 128
#define DI_ 256
#define DL_ 512
#define V_ 10000

// ws layout (bytes)
#define OFF_EMBH   0u          // V*DI fp16 = 5,120,000
#define OFF_WIT    5120000u    // [512][256] fp16 = 262,144 (WiT[n][k] = Wi[k][n])
#define OFF_WFRAG  5382144u    // 32 tiles x 16 kk x 64 lanes x 8 f16 = 524,288 (frag-linear Wh)
#define OFF_BSUM   5906432u    // 512 f32 = 2048 (bi + bh)

// fast tanh: 1 - 2/(exp(2x)+1). No clamp needed: exp2->inf gives 1, ->0 gives -1.
__device__ __forceinline__ float fast_tanh(float x) {
  float e = __builtin_amdgcn_exp2f(x * 2.88539008177793f);  // exp(2x)
  return 1.f - 2.f * __builtin_amdgcn_rcpf(e + 1.f);
}

// ---------------- prep kernels ----------------
__global__ void prep_emb_k(const float* __restrict__ emb, f16* __restrict__ embH, int n) {
  for (int i = blockIdx.x * blockDim.x + threadIdx.x; i < n; i += gridDim.x * blockDim.x)
    embH[i] = (f16)emb[i];
}

// WiT[n][k] = Wi[k][n]; Wfrag fragment-linear Wh (A/B-operand [n][k] layout); bsum = bi+bh
__global__ void prep_w_k(const float* __restrict__ Wi, const float* __restrict__ Wh,
                         const float* __restrict__ bi, const float* __restrict__ bh,
                         f16* __restrict__ WiT, f16* __restrict__ Wfrag,
                         float* __restrict__ bsum) {
  int i = blockIdx.x * blockDim.x + threadIdx.x;
  if (i < 131072) {                       // WiT
    int n = i & 511, k = i >> 9;
    WiT[n * 256 + k] = (f16)Wi[k * 512 + n];
  } else if (i < 131072 + 32768) {        // Wfrag[ct][kk][l][8]: lane l holds Wh[kbase+e][ct*16+(l&15)]
    int s = i - 131072;
    int l = s & 63, kk = (s >> 6) & 15, ct = s >> 10;
    int n = ct * 16 + (l & 15);
    int kbase = kk * 32 + (l >> 4) * 8;
    f16 tmp[8];
#pragma unroll
    for (int e = 0; e < 8; e++) tmp[e] = (f16)Wh[(size_t)(kbase + e) * 512 + n];
    *(f16x8*)&Wfrag[(size_t)s * 8] = *(f16x8*)tmp;
  } else if (i < 131072 + 32768 + 512) {  // bsum
    int s = i - 131072 - 32768;
    bsum[s] = bi[s] + bh[s];
  }
}

// ---------------- phase A: PREfrag = gather(embH,X) @ Wi + bsum ----------------
// SWAPPED MFMA (A=Wi fragment, B=emb fragment) -> D[n][m]: thread holds
// m=lane&15 (batch row), n=(lane>>4)*4+r (4 consecutive cols).
// PREfrag slot formula (shared with rnnB): t*65536 + c*8192 + ct*256 + lane*4 + r.
__global__ __launch_bounds__(256) void gemmA_k(
    const int* __restrict__ X, const f16* __restrict__ embH,
    const f16* __restrict__ WiT, const float* __restrict__ bsum,
    float* __restrict__ out) {
  __shared__ f16 Ah[128][40];
  __shared__ f16 Bh[128][40];
  __shared__ int idxL[128];

  int tid = threadIdx.x;
  int lane = tid & 63, w = tid >> 6;
  int wr = w >> 1, wc = w & 1;
  int by = blockIdx.y, bx = blockIdx.x;
  int m0 = by * 128, n0 = bx * 128;

  if (tid < 128) {
    int v = X[m0 + tid];
    idxL[tid] = (v < 0) ? 0 : ((v >= V_) ? (V_ - 1) : v);
  }
  __syncthreads();

  f32x4 acc[4][4];
#pragma unroll
  for (int i = 0; i < 4; i++)
#pragma unroll
    for (int jj = 0; jj < 4; jj++) acc[i][jj] = (f32x4){0.f, 0.f, 0.f, 0.f};

  int ar = lane & 15, koff = (lane >> 4) * 8, r0 = (lane >> 4) * 4;

  for (int kk = 0; kk < 8; kk++) {
    int k0 = kk * 32;
#pragma unroll
    for (int q = 0; q < 2; q++) {
      int s = tid + 256 * q;
      int row = s >> 2, part = s & 3;
      *(uint4*)&Ah[row][part * 8] = *(const uint4*)&embH[idxL[row] * 256 + k0 + part * 8];
      *(uint4*)&Bh[row][part * 8] = *(const uint4*)&WiT[(n0 + row) * 256 + k0 + part * 8];
    }
    __syncthreads();
    f16x8 a[4], b[4];
#pragma unroll
    for (int i = 0; i < 4; i++) a[i] = *(const f16x8*)&Ah[wr * 64 + i * 16 + ar][koff];
#pragma unroll
    for (int jj = 0; jj < 4; jj++) b[jj] = *(const f16x8*)&Bh[wc * 64 + jj * 16 + ar][koff];
#pragma unroll
    for (int i = 0; i < 4; i++)
#pragma unroll
      for (int jj = 0; jj < 4; jj++)   // SWAPPED: A=WiT frag, B=emb frag -> D[n][m]
        acc[i][jj] = __builtin_amdgcn_mfma_f32_16x16x32_f16(b[jj], a[i], acc[i][jj], 0, 0, 0);
    __syncthreads();
  }

#pragma unroll
  for (int i = 0; i < 4; i++) {
#pragma unroll
    for (int jj = 0; jj < 4; jj++) {
      int c = wr * 4 + i;
      int ct = bx * 8 + wc * 4 + jj;
      f32x4 bsv = *(const f32x4*)&bsum[ct * 16 + r0];  // cols vary with r
      f32x4 v = acc[i][jj];
      v[0] += bsv[0]; v[1] += bsv[1]; v[2] += bsv[2]; v[3] += bsv[3];
      *(f32x4*)&out[(size_t)by * 65536 + (size_t)c * 8192 + ct * 256 + lane * 4] = v;
    }
  }
}

// ---------------- phase B: persistent recurrence, ZERO inter-WG comms ----------------
// 8 WGs x 512 threads (2 waves/SIMD, 256-reg unified budget). Wave w owns
// col-tiles 4w..4w+3:
//   tiles 4w,4w+1: AGPR-pinned via no-op "+a" asm at init (allocator cannot
//                  remat; builtin MFMA reads AGPR operands directly on gfx950)
//   tile 4w+2:     LDS-resident (8 tiles = 128 KB)
//   tile 4w+3:     streamed from L2 each step, 16 plain per-kk loads
//                  (compiler hoists/pipelines them freely -- this scheduling
//                  freedom is what r9's asm k-loop destroyed)
// All MFMAs are builtins: compiler owns hazards + interleaving of the 4 chains.
#define RNN_STEP(T, PCUR, PNXT)                                               \
  {                                                                           \
    __syncthreads(); /* B1: hA(t-1) writes visible; drains all vmem */        \
    f32x4 acc0 = {0.f,0.f,0.f,0.f}, acc1 = {0.f,0.f,0.f,0.f};                 \
    f32x4 acc2 = {0.f,0.f,0.f,0.f}, acc3 = {0.f,0.f,0.f,0.f};                 \
    int tn_ = (T) + 1; if (tn_ >= 1024) tn_ = 0; /* dummy on last step */     \
    const f32x4* pb_ = (const f32x4*)(H + (size_t)tn_ * 65536 + (size_t)c * 8192); \
    _Pragma("unroll")                                                         \
    for (int kk = 0; kk < 16; kk++) {                                         \
      f16x8 a_  = *(const f16x8*)&hA[(kk * 64 + lane) * 8];                   \
      f16x8 wl_ = *(const f16x8*)&Wlds[((w * 16 + kk) * 64 + lane) * 8];      \
      f16x8 ws_ = Wfr[sbase + (kk << 6)];                                     \
      acc0 = __builtin_amdgcn_mfma_f32_16x16x32_f16(wa[kk],      a_, acc0, 0, 0, 0); \
      acc1 = __builtin_amdgcn_mfma_f32_16x16x32_f16(wa[16 + kk], a_, acc1, 0, 0, 0); \
      acc2 = __builtin_amdgcn_mfma_f32_16x16x32_f16(wl_,         a_, acc2, 0, 0, 0); \
      acc3 = __builtin_amdgcn_mfma_f32_16x16x32_f16(ws_,         a_, acc3, 0, 0, 0); \
      if (kk == 2) {                                                          \
        PNXT[0] = pb_[(w4 + 0) * 64 + lane];                                  \
        PNXT[1] = pb_[(w4 + 1) * 64 + lane];                                  \
        PNXT[2] = pb_[(w4 + 2) * 64 + lane];                                  \
        PNXT[3] = pb_[(w4 + 3) * 64 + lane];                                  \
      }                                                                       \
    }                                                                         \
    __syncthreads(); /* B2: hA(t-1) reads done -> safe to overwrite */        \
    float* Hrow_ = H + (size_t)(T) * 65536 + (size_t)c * 8192 + (size_t)(lane & 15) * 512; \
    f32x4 accs_[4] = {acc0, acc1, acc2, acc3};                                \
    _Pragma("unroll")                                                         \
    for (int ti = 0; ti < 4; ti++) {                                          \
      int ct_ = w4 + ti;                                                      \
      f32x4 o_; f16 hp_[4];                                                   \
      _Pragma("unroll")                                                       \
      for (int r = 0; r < 4; r++) {                                           \
        float v_ = fast_tanh(accs_[ti][r] + PCUR[ti][r]);                     \
        o_[r] = v_; hp_[r] = (f16)v_;                                         \
      }                                                                       \
      *(f32x4*)&Hrow_[ct_ * 16 + r0] = o_;                                    \
      int kH_ = ct_ * 16 + r0;                                                \
      int lH_ = (lane & 15) | (((kH_ >> 3) & 3) << 4);                        \
      *(f16x4*)&hA[(((kH_ >> 5) * 64 + lH_) << 3) + (kH_ & 7)] = *(f16x4*)hp_; \
    }                                                                         \
  }

__global__ void __launch_bounds__(512)
    __attribute__((amdgpu_waves_per_eu(2, 2))) rnnB_k(
    const float* __restrict__ h0, const f16* __restrict__ Wfrag,
    float* __restrict__ H) {
  __shared__ f16 Wlds[8 * 16 * 64 * 8];  // 131072 B: slot w <-> tile 4w+2
  __shared__ f16 hA[16 * 64 * 8];        // 16384 B: frag-linear h ([kk][lane][8])

  int tid = threadIdx.x, lane = tid & 63, w = tid >> 6;
  int c = blockIdx.x;          // batch slice: rows c*16..c*16+15
  int w4 = w * 4;
  int r0 = (lane >> 4) * 4;

  const f16x8* Wfr = (const f16x8*)Wfrag;  // index: (ct*16+kk)*64 + lane

  // one-time: LDS weight slots (slot s <- tile 4s+2)
  for (int idx = tid; idx < 8192; idx += 512) {
    int l = idx & 63, kk = (idx >> 6) & 15, s = idx >> 10;
    *(f16x8*)&Wlds[(size_t)idx * 8] = Wfr[((s * 4 + 2) * 16 + kk) * 64 + l];
  }
  // one-time: hA <- h0 (frag-linear scatter)
  for (int idx = tid; idx < 8192; idx += 512) {
    int kk = idx >> 9, l = (idx >> 3) & 63, e = idx & 7;
    int row = l & 15, k = kk * 32 + (l >> 4) * 8 + e;
    hA[idx] = (f16)h0[(size_t)(c * 16 + row) * 512 + k];
  }

  // one-time: AGPR-pinned weight tiles 4w, 4w+1 (128 AGPRs). The empty "+a"
  // asm forces each value through an AGPR and makes it non-rematerializable;
  // builtin MFMA then sources it directly (no asm MFMA, compiler owns hazards).
  f16x8 wa[32];
#pragma unroll
  for (int ti = 0; ti < 2; ti++)
#pragma unroll
    for (int kk = 0; kk < 16; kk++) {
      wa[ti * 16 + kk] = Wfr[((w4 + ti) * 16 + kk) * 64 + lane];
      asm volatile("" : "+a"(wa[ti * 16 + kk]));
    }

  // stream tile 4w+3: base index (16 fixed addresses, reloaded every step)
  int sbase = ((w4 + 3) * 16) * 64 + lane;

  // prologue: pre(t=0)
  f32x4 preA[4], preB[4];
  {
    const f32x4* pb = (const f32x4*)(H + (size_t)c * 8192);
#pragma unroll
    for (int ti = 0; ti < 4; ti++) preA[ti] = pb[(w4 + ti) * 64 + lane];
  }

  for (int s = 0; s < 512; s++) {
    RNN_STEP(2 * s,     preA, preB)   // k-loop issues preB <- PRE(2s+1)
    RNN_STEP(2 * s + 1, preB, preA)   // k-loop issues preA <- PRE(2s+2)
  }
}

// ---------------- launch ----------------
extern "C" void kernel_launch(void* const* d_in, const int* in_sizes, int n_in,
                              void* d_out, int out_size, void* d_ws, size_t ws_size,
                              hipStream_t stream) {
  const int* X     = (const int*)d_in[0];   // int32 (harness stores integer inputs as int32)
  const float* h0  = (const float*)d_in[1];
  const float* emb = (const float*)d_in[2];
  const float* Wi  = (const float*)d_in[3];
  const float* bi  = (const float*)d_in[4];
  const float* Wh  = (const float*)d_in[5];
  const float* bh  = (const float*)d_in[6];
  float* H = (float*)d_out;

  char* ws = (char*)d_ws;
  f16* embH   = (f16*)(ws + OFF_EMBH);
  f16* WiT    = (f16*)(ws + OFF_WIT);
  f16* Wfrag  = (f16*)(ws + OFF_WFRAG);
  float* bsum = (float*)(ws + OFF_BSUM);

  prep_emb_k<<<2560, 256, 0, stream>>>(emb, embH, V_ * DI_);
  prep_w_k<<<642, 256, 0, stream>>>(Wi, Wh, bi, bh, WiT, Wfrag, bsum);
  gemmA_k<<<dim3(4, 1024), 256, 0, stream>>>(X, embH, WiT, bsum, H);
  rnnB_k<<<8, 512, 0, stream>>>(h0, Wfrag, H);
}